// Round 10
// baseline (267.910 us; speedup 1.0000x reference)
//
#include <hip/hip_runtime.h>
#include <hip/hip_bf16.h>
#include <math.h>

#define NB   16
#define C1   256
#define C2   256
#define NK   5
#define NEXP (C2 * NK)   // 1280
#define HW   4096

typedef __attribute__((ext_vector_type(8))) short bf16x8;
typedef __attribute__((ext_vector_type(4))) float f32x4;

__device__ __forceinline__ unsigned short bfbits(float v) {
    return __builtin_bit_cast(unsigned short, __float2bfloat16(v));
}

// ---------------------------------------------------------------------------
__global__ void weff_kernel(const float* __restrict__ w_path, float* __restrict__ weff) {
    int idx = blockIdx.x * 256 + threadIdx.x;
    if (idx >= NK * C2 * 9) return;
    float s = 0.f;
    #pragma unroll
    for (int p = 0; p < 3; ++p)
        s += w_path[(long)p * NK * C2 * 9 + idx];
    weff[idx] = s;
}

__global__ void cvt_bf16_kernel(const float* __restrict__ in, __hip_bfloat16* __restrict__ out, int n) {
    int i = blockIdx.x * 256 + threadIdx.x;
    if (i < n) out[i] = __float2bfloat16(in[i]);
}

// ---------------------------------------------------------------------------
// Weight-stationary MFMA GEMM v2: K=256 in LDS, ONE barrier, 2 blocks/CU.
// Block: 512 thr / 8 waves; tile 256 m x 64 n x 256 k; LDS 32 KB.
// __launch_bounds__(512,4) caps VGPR at 128 -> 16 waves/CU = 2 blocks co-
// resident: one block's stage latency hides under the other's compute.
// Swizzle key = n&31 (R9-measured: 0 bank conflicts both sides).
// ---------------------------------------------------------------------------
template <bool FP32B, bool OUT_BF16>
__global__ __launch_bounds__(512, 4)
void ws_gemm_kernel(const __hip_bfloat16* __restrict__ A,   // [M][256] bf16
                    const void* __restrict__ B_all,         // [z][256][4096]
                    void* __restrict__ C_all,
                    long bStrideB, long bStrideC, int bOffB, int bOffC,
                    const float* __restrict__ bn_gamma, const float* __restrict__ bn_beta,
                    const float* __restrict__ bn_mean, const float* __restrict__ bn_var) {
    constexpr int KK = 256, NN = 4096;
    __shared__ __align__(16) char Bs[64 * 512];    // 32 KB
    const int z  = blockIdx.z;
    const int n0 = blockIdx.x * 64;
    const int m0 = blockIdx.y * 256;
    const int t  = threadIdx.x;
    const int lane = t & 63;
    const int wv = t >> 6;            // 0..7
    const int lr = lane & 15, lg = lane >> 4;

    // ---- W fragments, register-resident for the whole kernel
    bf16x8 af[2][8];
    const __hip_bfloat16* wp = A + (long)(m0 + wv * 32 + lr) * KK + lg * 8;
    #pragma unroll
    for (int s = 0; s < 2; ++s)
        #pragma unroll
        for (int ks = 0; ks < 8; ++ks)
            af[s][ks] = *(const bf16x8*)(wp + (long)s * 16 * KK + ks * 32);

    // ---- stage x tile: thread -> (n = t&63, k-section kb = (t>>6)*32)
    const int sn = t & 63;
    const int kb = (t >> 6) * 32;
    const int key = sn & 31;
    const char* Bbase = (const char*)B_all + (long)(bOffB + z) * bStrideB * (FP32B ? 4 : 2);
    #pragma unroll
    for (int gq = 0; gq < 2; ++gq) {               // 16 k's per group
        unsigned u[8];
        if constexpr (FP32B) {
            const float* p = (const float*)Bbase + (long)(kb + gq * 16) * NN + n0 + sn;
            #pragma unroll
            for (int i = 0; i < 8; ++i) {
                float v0 = p[(long)(2 * i) * NN];
                float v1 = p[(long)(2 * i + 1) * NN];
                u[i] = (unsigned)bfbits(v0) | ((unsigned)bfbits(v1) << 16);
            }
        } else {
            const unsigned short* p = (const unsigned short*)Bbase + (long)(kb + gq * 16) * NN + n0 + sn;
            #pragma unroll
            for (int i = 0; i < 8; ++i)
                u[i] = (unsigned)p[(long)(2 * i) * NN] |
                       ((unsigned)p[(long)(2 * i + 1) * NN] << 16);
        }
        const int ch0 = (kb >> 3) + gq * 2;        // logical 16B chunk index
        *(uint4*)(Bs + sn * 512 + ((ch0 ^ key) * 16))       = *(uint4*)&u[0];
        *(uint4*)(Bs + sn * 512 + (((ch0 + 1) ^ key) * 16)) = *(uint4*)&u[4];
    }
    __syncthreads();                                // the ONLY barrier

    // ---- compute: 8 ksteps x 4 nfrags, each B-frag feeds both m-strips
    f32x4 acc[2][4];
    #pragma unroll
    for (int s = 0; s < 2; ++s)
        #pragma unroll
        for (int j = 0; j < 4; ++j)
            acc[s][j] = (f32x4){0.f, 0.f, 0.f, 0.f};

    #pragma unroll
    for (int ks = 0; ks < 8; ++ks) {
        #pragma unroll
        for (int j = 0; j < 4; ++j) {
            const int n = j * 16 + lr;
            bf16x8 bfr = *(const bf16x8*)(Bs + n * 512 + (((ks * 4 + lg) ^ (n & 31)) * 16));
            acc[0][j] = __builtin_amdgcn_mfma_f32_16x16x32_bf16(bfr, af[0][ks], acc[0][j], 0, 0, 0);
            acc[1][j] = __builtin_amdgcn_mfma_f32_16x16x32_bf16(bfr, af[1][ks], acc[1][j], 0, 0, 0);
        }
    }

    // ---- epilogue: m = m0 + wv*32 + s*16 + lr ; n = n0 + j*16 + lg*4 + r
    if constexpr (OUT_BF16) {
        __hip_bfloat16* C = (__hip_bfloat16*)C_all + (long)(bOffC + z) * bStrideC;
        #pragma unroll
        for (int s = 0; s < 2; ++s) {
            const int m = m0 + wv * 32 + s * 16 + lr;
            #pragma unroll
            for (int j = 0; j < 4; ++j) {
                const long n = n0 + j * 16 + lg * 4;
                short4 sv;
                sv.x = (short)bfbits(acc[s][j][0]);
                sv.y = (short)bfbits(acc[s][j][1]);
                sv.z = (short)bfbits(acc[s][j][2]);
                sv.w = (short)bfbits(acc[s][j][3]);
                *(short4*)(C + (long)m * NN + n) = sv;
            }
        }
    } else {
        float* C = (float*)C_all + (long)(bOffC + z) * bStrideC;
        #pragma unroll
        for (int s = 0; s < 2; ++s) {
            const int m = m0 + wv * 32 + s * 16 + lr;
            const float scale = bn_gamma[m] * rsqrtf(bn_var[m] + 1e-5f);
            const float mn = bn_mean[m], bt = bn_beta[m];
            #pragma unroll
            for (int j = 0; j < 4; ++j) {
                const long n = n0 + j * 16 + lg * 4;
                float4 v;
                float t0 = (acc[s][j][0] - mn) * scale + bt;
                float t1 = (acc[s][j][1] - mn) * scale + bt;
                float t2 = (acc[s][j][2] - mn) * scale + bt;
                float t3 = (acc[s][j][3] - mn) * scale + bt;
                v.x = t0 / (1.0f + __expf(-t0));
                v.y = t1 / (1.0f + __expf(-t1));
                v.z = t2 / (1.0f + __expf(-t2));
                v.w = t3 / (1.0f + __expf(-t3));
                *(float4*)(C + (long)m * NN + n) = v;
            }
        }
    }
}

// ---------------------------------------------------------------------------
// Stage 2: roll + zero-padded depthwise 3x3 + sum over 5 shift groups.
// ---------------------------------------------------------------------------
__global__ __launch_bounds__(256)
void shift_dw_kernel(const __hip_bfloat16* __restrict__ xexp,  // [z][1280][4096]
                     const float* __restrict__ weff,           // [5][256][9]
                     __hip_bfloat16* __restrict__ merged) {    // [z][256][4096]
    __shared__ __align__(16) __hip_bfloat16 sd[NK * 34 * 64];  // 21760 B
    const int t  = threadIdx.x;
    const int r0 = blockIdx.x * 32;        // 0 or 32
    const int c  = blockIdx.y;
    const int z  = blockIdx.z;
    const int shifts[NK] = {-4, -1, 2, 5, 8};
    const __hip_bfloat16* base = xexp + ((long)z * NEXP + (long)c * NK) * HW;

    for (int idx = t; idx < NK * 34 * 8; idx += 256) {
        int k   = idx / (34 * 8);
        int rem = idx - k * (34 * 8);
        int rr  = rem >> 3, ch = (rem & 7) * 8;
        int grow = (r0 - 1 + rr - shifts[k]) & 63;
        *(bf16x8*)&sd[(k * 34 + rr) * 64 + ch] =
            *(const bf16x8*)(base + (long)k * HW + grow * 64 + ch);
    }
    __syncthreads();

    const int j  = t & 63;
    const int ty = t >> 6;                 // 0..3
    const int pbase = ty * 8;
    const bool topEdge = (r0 == 0)  && (ty == 0);
    const bool botEdge = (r0 == 32) && (ty == 3);

    float2 acc[4];
    #pragma unroll
    for (int i = 0; i < 4; ++i) acc[i] = (float2){0.f, 0.f};

    #pragma unroll
    for (int k = 0; k < NK; ++k) {
        const int s = shifts[k];
        const int cL = (j - 1 - s) & 63;
        const int cC = (j - s) & 63;
        const int cR = (j + 1 - s) & 63;
        const float* wp = &weff[((long)k * C2 + c) * 9];
        float w[9];
        #pragma unroll
        for (int i = 0; i < 9; ++i) w[i] = wp[i];
        if (j == 0)  { w[0] = 0.f; w[3] = 0.f; w[6] = 0.f; }
        if (j == 63) { w[2] = 0.f; w[5] = 0.f; w[8] = 0.f; }
        const __hip_bfloat16* pl = &sd[k * 34 * 64];

        float vL[4], vC[4], vR[4];
        #pragma unroll
        for (int w4 = 0; w4 < 4; ++w4) {
            vL[w4] = __bfloat162float(pl[(pbase + w4) * 64 + cL]);
            vC[w4] = __bfloat162float(pl[(pbase + w4) * 64 + cC]);
            vR[w4] = __bfloat162float(pl[(pbase + w4) * 64 + cR]);
        }
        if (topEdge) { vL[0] = 0.f; vC[0] = 0.f; vR[0] = 0.f; }

        #pragma unroll
        for (int pr = 0; pr < 4; ++pr) {
            #pragma unroll
            for (int u = 0; u < 3; ++u) {
                const int wi  = (2 * pr + u) & 3;
                const int wi2 = (2 * pr + u + 1) & 3;
                acc[pr].x += w[u*3+0] * vL[wi]  + w[u*3+1] * vC[wi]  + w[u*3+2] * vR[wi];
                acc[pr].y += w[u*3+0] * vL[wi2] + w[u*3+1] * vC[wi2] + w[u*3+2] * vR[wi2];
            }
            if (pr < 3) {
                const int na = (2 * pr) & 3, nb = (2 * pr + 1) & 3;
                const int ra = pbase + 2 * pr + 4, rb = pbase + 2 * pr + 5;
                vL[na] = __bfloat162float(pl[ra * 64 + cL]);
                vC[na] = __bfloat162float(pl[ra * 64 + cC]);
                vR[na] = __bfloat162float(pl[ra * 64 + cR]);
                vL[nb] = __bfloat162float(pl[rb * 64 + cL]);
                vC[nb] = __bfloat162float(pl[rb * 64 + cC]);
                vR[nb] = __bfloat162float(pl[rb * 64 + cR]);
                if (botEdge && pr == 2) { vL[nb] = 0.f; vC[nb] = 0.f; vR[nb] = 0.f; }
            }
        }
    }

    long outb = ((long)z * C2 + c) * HW + (long)(r0 + ty * 8) * 64 + j;
    #pragma unroll
    for (int pr = 0; pr < 4; ++pr) {
        merged[outb + (long)(2 * pr) * 64]     = __float2bfloat16(acc[pr].x);
        merged[outb + (long)(2 * pr + 1) * 64] = __float2bfloat16(acc[pr].y);
    }
}

// ---------------------------------------------------------------------------
extern "C" void kernel_launch(void* const* d_in, const int* in_sizes, int n_in,
                              void* d_out, int out_size, void* d_ws, size_t ws_size,
                              hipStream_t stream) {
    const float* x        = (const float*)d_in[0];
    const float* w_expand = (const float*)d_in[1];
    const float* w_path   = (const float*)d_in[2];
    const float* w_mix    = (const float*)d_in[3];
    const float* bn_gamma = (const float*)d_in[4];
    const float* bn_beta  = (const float*)d_in[5];
    const float* bn_mean  = (const float*)d_in[6];
    const float* bn_var   = (const float*)d_in[7];

    char* ws = (char*)d_ws;
    float* weff             = (float*)ws;
    __hip_bfloat16* wexp_bf = (__hip_bfloat16*)(ws + 65536);
    __hip_bfloat16* wmix_bf = (__hip_bfloat16*)(ws + 65536 + 655360);
    const size_t head = 1 << 20;

    const size_t xe_per = (size_t)NEXP * HW * 2;   // 10 MB
    const size_t mg_per = (size_t)C2 * HW * 2;     // 2 MB
    const size_t per_b = xe_per + mg_per;          // 12 MB

    int g = 1;
    if (ws_size > head + per_b) {
        size_t fit = (ws_size - head) / per_b;
        g = (int)(fit < NB ? fit : NB);
        if (g < 1) g = 1;
    }

    char* p = ws + head;
    __hip_bfloat16* xexp   = (__hip_bfloat16*)p; p += (size_t)g * xe_per;
    __hip_bfloat16* merged = (__hip_bfloat16*)p;

    weff_kernel<<<(NK * C2 * 9 + 255) / 256, 256, 0, stream>>>(w_path, weff);
    cvt_bf16_kernel<<<(NEXP * C1 + 255) / 256, 256, 0, stream>>>(w_expand, wexp_bf, NEXP * C1);
    cvt_bf16_kernel<<<(C2 * C2 + 255) / 256, 256, 0, stream>>>(w_mix, wmix_bf, C2 * C2);

    for (int b0 = 0; b0 < NB; b0 += g) {
        int gb = (NB - b0) < g ? (NB - b0) : g;
        // expand: A = wexp_bf [1280x256], B = x [z][256][4096] fp32 -> xexp bf16
        ws_gemm_kernel<true, true><<<dim3(HW / 64, NEXP / 256, gb), 512, 0, stream>>>(
            wexp_bf, x, xexp,
            (long)C1 * HW, (long)NEXP * HW, b0, 0,
            nullptr, nullptr, nullptr, nullptr);
        shift_dw_kernel<<<dim3(2, C2, gb), 256, 0, stream>>>(xexp, weff, merged);
        // mix: A = wmix_bf [256x256], B = merged [z][256][4096] bf16 -> d_out fp32
        ws_gemm_kernel<false, false><<<dim3(HW / 64, 1, gb), 512, 0, stream>>>(
            wmix_bf, merged, d_out,
            (long)C2 * HW, (long)C2 * HW, 0, b0,
            bn_gamma, bn_beta, bn_mean, bn_var);
    }
}

// Round 11
// 238.119 us; speedup vs baseline: 1.1251x; 1.1251x over previous
//
#include <hip/hip_runtime.h>
#include <hip/hip_bf16.h>
#include <math.h>

#define NB   16
#define C1   256
#define C2   256
#define NK   5
#define NEXP (C2 * NK)   // 1280
#define HW   4096

typedef __attribute__((ext_vector_type(8))) short bf16x8;
typedef __attribute__((ext_vector_type(4))) float f32x4;

__device__ __forceinline__ unsigned short bfbits(float v) {
    return __builtin_bit_cast(unsigned short, __float2bfloat16(v));
}

// ---------------------------------------------------------------------------
__global__ void weff_kernel(const float* __restrict__ w_path, float* __restrict__ weff) {
    int idx = blockIdx.x * 256 + threadIdx.x;
    if (idx >= NK * C2 * 9) return;
    float s = 0.f;
    #pragma unroll
    for (int p = 0; p < 3; ++p)
        s += w_path[(long)p * NK * C2 * 9 + idx];
    weff[idx] = s;
}

__global__ void cvt_bf16_kernel(const float* __restrict__ in, __hip_bfloat16* __restrict__ out, int n) {
    int i = blockIdx.x * 256 + threadIdx.x;
    if (i < n) out[i] = __float2bfloat16(in[i]);
}

// ---------------------------------------------------------------------------
// N-streaming weight-stationary MFMA GEMM.
// Block: 512 thr / 8 waves; m-tile 256; K=256 resident (af in VGPRs);
// streams NCH chunks of n=64. Per chunk: issue loads for chunk+1 (raw in
// regs), compute FULL K reduction (~3K cy >> load latency), per-chunk
// epilogue, pack+ds_write chunk+1 (aged loads, no stall), ONE barrier.
// Swizzle key = n&31 (R9-measured 0 conflicts). Swapped-operand epilogue
// (R5-R10-verified mapping).
// ---------------------------------------------------------------------------
template <int NCH, bool FP32B, bool OUT_BF16>
__global__ __launch_bounds__(512, 2)
void nstream_gemm_kernel(const __hip_bfloat16* __restrict__ A,   // [M][256] bf16
                         const void* __restrict__ B_all,         // [z][256][4096]
                         void* __restrict__ C_all,
                         long bStrideB, long bStrideC, int bOffB, int bOffC,
                         const float* __restrict__ bn_gamma, const float* __restrict__ bn_beta,
                         const float* __restrict__ bn_mean, const float* __restrict__ bn_var) {
    constexpr int KK = 256, NN = 4096;
    __shared__ __align__(16) char Bs[2][64 * 512];   // 2 x 32 KB
    const int z  = blockIdx.z;
    const int nBase = blockIdx.x * (64 * NCH);
    const int m0 = blockIdx.y * 256;
    const int t  = threadIdx.x;
    const int lane = t & 63;
    const int wv = t >> 6;            // 0..7
    const int lr = lane & 15, lg = lane >> 4;

    // ---- W fragments, register-resident
    bf16x8 af[2][8];
    const __hip_bfloat16* wp = A + (long)(m0 + wv * 32 + lr) * KK + lg * 8;
    #pragma unroll
    for (int s = 0; s < 2; ++s)
        #pragma unroll
        for (int ks = 0; ks < 8; ++ks)
            af[s][ks] = *(const bf16x8*)(wp + (long)s * 16 * KK + ks * 32);

    // ---- BN params hoisted (per-m, constant across chunks)
    float scl[2], mnv[2], btv[2];
    if constexpr (!OUT_BF16) {
        #pragma unroll
        for (int s = 0; s < 2; ++s) {
            const int m = m0 + wv * 32 + s * 16 + lr;
            scl[s] = bn_gamma[m] * rsqrtf(bn_var[m] + 1e-5f);
            mnv[s] = bn_mean[m];
            btv[s] = bn_beta[m];
        }
    }

    // ---- staging ids: n-col sn (0..63), k-section kb = (t>>6)*32
    const int sn = t & 63;
    const int kb = (t >> 6) * 32;
    const int key = sn & 31;
    const char* Bbase = (const char*)B_all + (long)(bOffB + z) * bStrideB * (FP32B ? 4 : 2);

    float    fr[32];   // raw staged fp32 (expand path)
    unsigned hr[32];   // raw staged bf16 (mix path)

    auto issueB = [&](int ci) {
        const int nc = nBase + ci * 64 + sn;
        #pragma unroll
        for (int gq = 0; gq < 2; ++gq) {
            if constexpr (FP32B) {
                const float* p = (const float*)Bbase + (long)(kb + gq * 16) * NN + nc;
                #pragma unroll
                for (int i = 0; i < 16; ++i) fr[gq * 16 + i] = p[(long)i * NN];
            } else {
                const unsigned short* p = (const unsigned short*)Bbase + (long)(kb + gq * 16) * NN + nc;
                #pragma unroll
                for (int i = 0; i < 16; ++i) hr[gq * 16 + i] = p[(long)i * NN];
            }
        }
    };
    auto writeB = [&](int ci) {
        char* buf = Bs[ci & 1];
        #pragma unroll
        for (int gq = 0; gq < 2; ++gq) {
            unsigned u[8];
            #pragma unroll
            for (int i = 0; i < 8; ++i) {
                if constexpr (FP32B)
                    u[i] = (unsigned)bfbits(fr[gq * 16 + 2 * i]) |
                           ((unsigned)bfbits(fr[gq * 16 + 2 * i + 1]) << 16);
                else
                    u[i] = (hr[gq * 16 + 2 * i] & 0xffffu) | (hr[gq * 16 + 2 * i + 1] << 16);
            }
            const int ch0 = (kb >> 3) + gq * 2;
            *(uint4*)(buf + sn * 512 + ((ch0 ^ key) * 16))       = *(uint4*)&u[0];
            *(uint4*)(buf + sn * 512 + (((ch0 + 1) ^ key) * 16)) = *(uint4*)&u[4];
        }
    };

    // ---- prologue: stage chunk 0 (latency exposed once per block)
    issueB(0);
    writeB(0);
    __syncthreads();

    #pragma unroll
    for (int ci = 0; ci < NCH; ++ci) {
        if (ci + 1 < NCH) issueB(ci + 1);            // issue-early (T14)
        __builtin_amdgcn_sched_barrier(0);           // pin loads above compute
        const char* buf = Bs[ci & 1];

        f32x4 acc[2][4];
        #pragma unroll
        for (int s = 0; s < 2; ++s)
            #pragma unroll
            for (int j = 0; j < 4; ++j)
                acc[s][j] = (f32x4){0.f, 0.f, 0.f, 0.f};

        #pragma unroll
        for (int ks = 0; ks < 8; ++ks) {
            #pragma unroll
            for (int j = 0; j < 4; ++j) {
                const int n = j * 16 + lr;
                bf16x8 bfr = *(const bf16x8*)(buf + n * 512 + (((ks * 4 + lg) ^ (n & 31)) * 16));
                acc[0][j] = __builtin_amdgcn_mfma_f32_16x16x32_bf16(bfr, af[0][ks], acc[0][j], 0, 0, 0);
                acc[1][j] = __builtin_amdgcn_mfma_f32_16x16x32_bf16(bfr, af[1][ks], acc[1][j], 0, 0, 0);
            }
        }

        // ---- per-chunk epilogue: m = m0+wv*32+s*16+lr ; n = ncb+j*16+lg*4+r
        const int ncb = nBase + ci * 64;
        if constexpr (OUT_BF16) {
            __hip_bfloat16* C = (__hip_bfloat16*)C_all + (long)(bOffC + z) * bStrideC;
            #pragma unroll
            for (int s = 0; s < 2; ++s) {
                const int m = m0 + wv * 32 + s * 16 + lr;
                #pragma unroll
                for (int j = 0; j < 4; ++j) {
                    const long n = ncb + j * 16 + lg * 4;
                    short4 sv;
                    sv.x = (short)bfbits(acc[s][j][0]);
                    sv.y = (short)bfbits(acc[s][j][1]);
                    sv.z = (short)bfbits(acc[s][j][2]);
                    sv.w = (short)bfbits(acc[s][j][3]);
                    *(short4*)(C + (long)m * NN + n) = sv;
                }
            }
        } else {
            float* C = (float*)C_all + (long)(bOffC + z) * bStrideC;
            #pragma unroll
            for (int s = 0; s < 2; ++s) {
                const int m = m0 + wv * 32 + s * 16 + lr;
                #pragma unroll
                for (int j = 0; j < 4; ++j) {
                    const long n = ncb + j * 16 + lg * 4;
                    float4 v;
                    float t0 = (acc[s][j][0] - mnv[s]) * scl[s] + btv[s];
                    float t1 = (acc[s][j][1] - mnv[s]) * scl[s] + btv[s];
                    float t2 = (acc[s][j][2] - mnv[s]) * scl[s] + btv[s];
                    float t3 = (acc[s][j][3] - mnv[s]) * scl[s] + btv[s];
                    v.x = t0 / (1.0f + __expf(-t0));
                    v.y = t1 / (1.0f + __expf(-t1));
                    v.z = t2 / (1.0f + __expf(-t2));
                    v.w = t3 / (1.0f + __expf(-t3));
                    *(float4*)(C + (long)m * NN + n) = v;
                }
            }
        }

        if (ci + 1 < NCH) {
            writeB(ci + 1);          // aged loads -> minimal vmcnt stall
            __syncthreads();         // ONE barrier per chunk
        }
    }
}

// ---------------------------------------------------------------------------
// Stage 2: roll + zero-padded depthwise 3x3 + sum over 5 shift groups.
// ---------------------------------------------------------------------------
__global__ __launch_bounds__(256)
void shift_dw_kernel(const __hip_bfloat16* __restrict__ xexp,  // [z][1280][4096]
                     const float* __restrict__ weff,           // [5][256][9]
                     __hip_bfloat16* __restrict__ merged) {    // [z][256][4096]
    __shared__ __align__(16) __hip_bfloat16 sd[NK * 34 * 64];  // 21760 B
    const int t  = threadIdx.x;
    const int r0 = blockIdx.x * 32;        // 0 or 32
    const int c  = blockIdx.y;
    const int z  = blockIdx.z;
    const int shifts[NK] = {-4, -1, 2, 5, 8};
    const __hip_bfloat16* base = xexp + ((long)z * NEXP + (long)c * NK) * HW;

    for (int idx = t; idx < NK * 34 * 8; idx += 256) {
        int k   = idx / (34 * 8);
        int rem = idx - k * (34 * 8);
        int rr  = rem >> 3, ch = (rem & 7) * 8;
        int grow = (r0 - 1 + rr - shifts[k]) & 63;
        *(bf16x8*)&sd[(k * 34 + rr) * 64 + ch] =
            *(const bf16x8*)(base + (long)k * HW + grow * 64 + ch);
    }
    __syncthreads();

    const int j  = t & 63;
    const int ty = t >> 6;                 // 0..3
    const int pbase = ty * 8;
    const bool topEdge = (r0 == 0)  && (ty == 0);
    const bool botEdge = (r0 == 32) && (ty == 3);

    float2 acc[4];
    #pragma unroll
    for (int i = 0; i < 4; ++i) acc[i] = (float2){0.f, 0.f};

    #pragma unroll
    for (int k = 0; k < NK; ++k) {
        const int s = shifts[k];
        const int cL = (j - 1 - s) & 63;
        const int cC = (j - s) & 63;
        const int cR = (j + 1 - s) & 63;
        const float* wp = &weff[((long)k * C2 + c) * 9];
        float w[9];
        #pragma unroll
        for (int i = 0; i < 9; ++i) w[i] = wp[i];
        if (j == 0)  { w[0] = 0.f; w[3] = 0.f; w[6] = 0.f; }
        if (j == 63) { w[2] = 0.f; w[5] = 0.f; w[8] = 0.f; }
        const __hip_bfloat16* pl = &sd[k * 34 * 64];

        float vL[4], vC[4], vR[4];
        #pragma unroll
        for (int w4 = 0; w4 < 4; ++w4) {
            vL[w4] = __bfloat162float(pl[(pbase + w4) * 64 + cL]);
            vC[w4] = __bfloat162float(pl[(pbase + w4) * 64 + cC]);
            vR[w4] = __bfloat162float(pl[(pbase + w4) * 64 + cR]);
        }
        if (topEdge) { vL[0] = 0.f; vC[0] = 0.f; vR[0] = 0.f; }

        #pragma unroll
        for (int pr = 0; pr < 4; ++pr) {
            #pragma unroll
            for (int u = 0; u < 3; ++u) {
                const int wi  = (2 * pr + u) & 3;
                const int wi2 = (2 * pr + u + 1) & 3;
                acc[pr].x += w[u*3+0] * vL[wi]  + w[u*3+1] * vC[wi]  + w[u*3+2] * vR[wi];
                acc[pr].y += w[u*3+0] * vL[wi2] + w[u*3+1] * vC[wi2] + w[u*3+2] * vR[wi2];
            }
            if (pr < 3) {
                const int na = (2 * pr) & 3, nb = (2 * pr + 1) & 3;
                const int ra = pbase + 2 * pr + 4, rb = pbase + 2 * pr + 5;
                vL[na] = __bfloat162float(pl[ra * 64 + cL]);
                vC[na] = __bfloat162float(pl[ra * 64 + cC]);
                vR[na] = __bfloat162float(pl[ra * 64 + cR]);
                vL[nb] = __bfloat162float(pl[rb * 64 + cL]);
                vC[nb] = __bfloat162float(pl[rb * 64 + cC]);
                vR[nb] = __bfloat162float(pl[rb * 64 + cR]);
                if (botEdge && pr == 2) { vL[nb] = 0.f; vC[nb] = 0.f; vR[nb] = 0.f; }
            }
        }
    }

    long outb = ((long)z * C2 + c) * HW + (long)(r0 + ty * 8) * 64 + j;
    #pragma unroll
    for (int pr = 0; pr < 4; ++pr) {
        merged[outb + (long)(2 * pr) * 64]     = __float2bfloat16(acc[pr].x);
        merged[outb + (long)(2 * pr + 1) * 64] = __float2bfloat16(acc[pr].y);
    }
}

// ---------------------------------------------------------------------------
extern "C" void kernel_launch(void* const* d_in, const int* in_sizes, int n_in,
                              void* d_out, int out_size, void* d_ws, size_t ws_size,
                              hipStream_t stream) {
    const float* x        = (const float*)d_in[0];
    const float* w_expand = (const float*)d_in[1];
    const float* w_path   = (const float*)d_in[2];
    const float* w_mix    = (const float*)d_in[3];
    const float* bn_gamma = (const float*)d_in[4];
    const float* bn_beta  = (const float*)d_in[5];
    const float* bn_mean  = (const float*)d_in[6];
    const float* bn_var   = (const float*)d_in[7];

    char* ws = (char*)d_ws;
    float* weff             = (float*)ws;
    __hip_bfloat16* wexp_bf = (__hip_bfloat16*)(ws + 65536);
    __hip_bfloat16* wmix_bf = (__hip_bfloat16*)(ws + 65536 + 655360);
    const size_t head = 1 << 20;

    const size_t xe_per = (size_t)NEXP * HW * 2;   // 10 MB
    const size_t mg_per = (size_t)C2 * HW * 2;     // 2 MB
    const size_t per_b = xe_per + mg_per;          // 12 MB

    int g = 1;
    if (ws_size > head + per_b) {
        size_t fit = (ws_size - head) / per_b;
        g = (int)(fit < NB ? fit : NB);
        if (g < 1) g = 1;
    }

    char* p = ws + head;
    __hip_bfloat16* xexp   = (__hip_bfloat16*)p; p += (size_t)g * xe_per;
    __hip_bfloat16* merged = (__hip_bfloat16*)p;

    weff_kernel<<<(NK * C2 * 9 + 255) / 256, 256, 0, stream>>>(w_path, weff);
    cvt_bf16_kernel<<<(NEXP * C1 + 255) / 256, 256, 0, stream>>>(w_expand, wexp_bf, NEXP * C1);
    cvt_bf16_kernel<<<(C2 * C2 + 255) / 256, 256, 0, stream>>>(w_mix, wmix_bf, C2 * C2);

    for (int b0 = 0; b0 < NB; b0 += g) {
        int gb = (NB - b0) < g ? (NB - b0) : g;
        // expand: A = wexp_bf [1280x256], B = x [z][256][4096] fp32 -> xexp bf16
        nstream_gemm_kernel<4, true, true><<<dim3(HW / 256, NEXP / 256, gb), 512, 0, stream>>>(
            wexp_bf, x, xexp,
            (long)C1 * HW, (long)NEXP * HW, b0, 0,
            nullptr, nullptr, nullptr, nullptr);
        shift_dw_kernel<<<dim3(2, C2, gb), 256, 0, stream>>>(xexp, weff, merged);
        // mix: A = wmix_bf [256x256], B = merged [z][256][4096] bf16 -> d_out fp32
        nstream_gemm_kernel<2, false, false><<<dim3(HW / 128, 1, gb), 512, 0, stream>>>(
            wmix_bf, merged, d_out,
            (long)C2 * HW, (long)C2 * HW, 0, b0,
            bn_gamma, bn_beta, bn_mean, bn_var);
    }
}

// Round 12
// 237.944 us; speedup vs baseline: 1.1259x; 1.0007x over previous
//
#include <hip/hip_runtime.h>
#include <hip/hip_bf16.h>
#include <math.h>

#define NB   16
#define C1   256
#define C2   256
#define NK   5
#define NEXP (C2 * NK)   // 1280
#define HW   4096

typedef __attribute__((ext_vector_type(8))) short bf16x8;
typedef __attribute__((ext_vector_type(4))) float f32x4;

__device__ __forceinline__ unsigned short bfbits(float v) {
    return __builtin_bit_cast(unsigned short, __float2bfloat16(v));
}

// lgkm-only barrier: ds ops drained, VMEM (loads/stores) stay in flight (T4)
#define LGKM_BARRIER() do { \
    asm volatile("s_waitcnt lgkmcnt(0)" ::: "memory"); \
    __builtin_amdgcn_sched_barrier(0); \
    __builtin_amdgcn_s_barrier(); } while (0)

// ---------------------------------------------------------------------------
__global__ void weff_kernel(const float* __restrict__ w_path, float* __restrict__ weff) {
    int idx = blockIdx.x * 256 + threadIdx.x;
    if (idx >= NK * C2 * 9) return;
    float s = 0.f;
    #pragma unroll
    for (int p = 0; p < 3; ++p)
        s += w_path[(long)p * NK * C2 * 9 + idx];
    weff[idx] = s;
}

__global__ void cvt_bf16_kernel(const float* __restrict__ in, __hip_bfloat16* __restrict__ out, int n) {
    int i = blockIdx.x * 256 + threadIdx.x;
    if (i < n) out[i] = __float2bfloat16(in[i]);
}

// ---------------------------------------------------------------------------
// N-streaming weight-stationary MFMA GEMM (R11 structure + T4/T5 polish).
// Per chunk: issue loads for chunk+1 -> compute full-K reduction (setprio 1)
// -> pack+ds_write chunk+1 (aged loads) -> epilogue stores -> lgkm-only
// barrier (stores/loads NOT drained).
// ---------------------------------------------------------------------------
template <int NCH, bool FP32B, bool OUT_BF16>
__global__ __launch_bounds__(512, 2)
void nstream_gemm_kernel(const __hip_bfloat16* __restrict__ A,   // [M][256] bf16
                         const void* __restrict__ B_all,         // [z][256][4096]
                         void* __restrict__ C_all,
                         long bStrideB, long bStrideC, int bOffB, int bOffC,
                         const float* __restrict__ bn_gamma, const float* __restrict__ bn_beta,
                         const float* __restrict__ bn_mean, const float* __restrict__ bn_var) {
    constexpr int KK = 256, NN = 4096;
    __shared__ __align__(16) char Bs[2][64 * 512];   // 2 x 32 KB
    const int z  = blockIdx.z;
    const int nBase = blockIdx.x * (64 * NCH);
    const int m0 = blockIdx.y * 256;
    const int t  = threadIdx.x;
    const int lane = t & 63;
    const int wv = t >> 6;            // 0..7
    const int lr = lane & 15, lg = lane >> 4;

    // ---- W fragments, register-resident
    bf16x8 af[2][8];
    const __hip_bfloat16* wp = A + (long)(m0 + wv * 32 + lr) * KK + lg * 8;
    #pragma unroll
    for (int s = 0; s < 2; ++s)
        #pragma unroll
        for (int ks = 0; ks < 8; ++ks)
            af[s][ks] = *(const bf16x8*)(wp + (long)s * 16 * KK + ks * 32);

    // ---- BN params hoisted
    float scl[2], mnv[2], btv[2];
    if constexpr (!OUT_BF16) {
        #pragma unroll
        for (int s = 0; s < 2; ++s) {
            const int m = m0 + wv * 32 + s * 16 + lr;
            scl[s] = bn_gamma[m] * rsqrtf(bn_var[m] + 1e-5f);
            mnv[s] = bn_mean[m];
            btv[s] = bn_beta[m];
        }
    }

    // ---- staging ids
    const int sn = t & 63;
    const int kb = (t >> 6) * 32;
    const int key = sn & 31;
    const char* Bbase = (const char*)B_all + (long)(bOffB + z) * bStrideB * (FP32B ? 4 : 2);

    float    fr[32];
    unsigned hr[32];

    auto issueB = [&](int ci) {
        const int nc = nBase + ci * 64 + sn;
        #pragma unroll
        for (int gq = 0; gq < 2; ++gq) {
            if constexpr (FP32B) {
                const float* p = (const float*)Bbase + (long)(kb + gq * 16) * NN + nc;
                #pragma unroll
                for (int i = 0; i < 16; ++i) fr[gq * 16 + i] = p[(long)i * NN];
            } else {
                const unsigned short* p = (const unsigned short*)Bbase + (long)(kb + gq * 16) * NN + nc;
                #pragma unroll
                for (int i = 0; i < 16; ++i) hr[gq * 16 + i] = p[(long)i * NN];
            }
        }
    };
    auto writeB = [&](int ci) {
        char* buf = Bs[ci & 1];
        #pragma unroll
        for (int gq = 0; gq < 2; ++gq) {
            unsigned u[8];
            #pragma unroll
            for (int i = 0; i < 8; ++i) {
                if constexpr (FP32B)
                    u[i] = (unsigned)bfbits(fr[gq * 16 + 2 * i]) |
                           ((unsigned)bfbits(fr[gq * 16 + 2 * i + 1]) << 16);
                else
                    u[i] = (hr[gq * 16 + 2 * i] & 0xffffu) | (hr[gq * 16 + 2 * i + 1] << 16);
            }
            const int ch0 = (kb >> 3) + gq * 2;
            *(uint4*)(buf + sn * 512 + ((ch0 ^ key) * 16))       = *(uint4*)&u[0];
            *(uint4*)(buf + sn * 512 + (((ch0 + 1) ^ key) * 16)) = *(uint4*)&u[4];
        }
    };

    // ---- prologue: stage chunk 0
    issueB(0);
    writeB(0);
    LGKM_BARRIER();

    #pragma unroll
    for (int ci = 0; ci < NCH; ++ci) {
        if (ci + 1 < NCH) {
            issueB(ci + 1);                          // issue-early (T14)
            __builtin_amdgcn_sched_barrier(0);       // pin loads above compute
        }
        const char* buf = Bs[ci & 1];

        f32x4 acc[2][4];
        #pragma unroll
        for (int s = 0; s < 2; ++s)
            #pragma unroll
            for (int j = 0; j < 4; ++j)
                acc[s][j] = (f32x4){0.f, 0.f, 0.f, 0.f};

        __builtin_amdgcn_s_setprio(1);               // T5
        #pragma unroll
        for (int ks = 0; ks < 8; ++ks) {
            #pragma unroll
            for (int j = 0; j < 4; ++j) {
                const int n = j * 16 + lr;
                bf16x8 bfr = *(const bf16x8*)(buf + n * 512 + (((ks * 4 + lg) ^ (n & 31)) * 16));
                acc[0][j] = __builtin_amdgcn_mfma_f32_16x16x32_bf16(bfr, af[0][ks], acc[0][j], 0, 0, 0);
                acc[1][j] = __builtin_amdgcn_mfma_f32_16x16x32_bf16(bfr, af[1][ks], acc[1][j], 0, 0, 0);
            }
        }
        __builtin_amdgcn_s_setprio(0);

        if (ci + 1 < NCH) writeB(ci + 1);            // aged loads -> short wait

        // ---- per-chunk epilogue (stores left in flight across the barrier)
        const int ncb = nBase + ci * 64;
        if constexpr (OUT_BF16) {
            __hip_bfloat16* C = (__hip_bfloat16*)C_all + (long)(bOffC + z) * bStrideC;
            #pragma unroll
            for (int s = 0; s < 2; ++s) {
                const int m = m0 + wv * 32 + s * 16 + lr;
                #pragma unroll
                for (int j = 0; j < 4; ++j) {
                    const long n = ncb + j * 16 + lg * 4;
                    short4 sv;
                    sv.x = (short)bfbits(acc[s][j][0]);
                    sv.y = (short)bfbits(acc[s][j][1]);
                    sv.z = (short)bfbits(acc[s][j][2]);
                    sv.w = (short)bfbits(acc[s][j][3]);
                    *(short4*)(C + (long)m * NN + n) = sv;
                }
            }
        } else {
            float* C = (float*)C_all + (long)(bOffC + z) * bStrideC;
            #pragma unroll
            for (int s = 0; s < 2; ++s) {
                const int m = m0 + wv * 32 + s * 16 + lr;
                #pragma unroll
                for (int j = 0; j < 4; ++j) {
                    const long n = ncb + j * 16 + lg * 4;
                    float4 v;
                    float t0 = (acc[s][j][0] - mnv[s]) * scl[s] + btv[s];
                    float t1 = (acc[s][j][1] - mnv[s]) * scl[s] + btv[s];
                    float t2 = (acc[s][j][2] - mnv[s]) * scl[s] + btv[s];
                    float t3 = (acc[s][j][3] - mnv[s]) * scl[s] + btv[s];
                    v.x = t0 / (1.0f + __expf(-t0));
                    v.y = t1 / (1.0f + __expf(-t1));
                    v.z = t2 / (1.0f + __expf(-t2));
                    v.w = t3 / (1.0f + __expf(-t3));
                    *(float4*)(C + (long)m * NN + n) = v;
                }
            }
        }

        if (ci + 1 < NCH) LGKM_BARRIER();            // ds visible, VMEM in flight
    }
}

// ---------------------------------------------------------------------------
// Stage 2: roll + zero-padded depthwise 3x3 + sum over 5 shift groups.
// ---------------------------------------------------------------------------
__global__ __launch_bounds__(256)
void shift_dw_kernel(const __hip_bfloat16* __restrict__ xexp,  // [z][1280][4096]
                     const float* __restrict__ weff,           // [5][256][9]
                     __hip_bfloat16* __restrict__ merged) {    // [z][256][4096]
    __shared__ __align__(16) __hip_bfloat16 sd[NK * 34 * 64];  // 21760 B
    const int t  = threadIdx.x;
    const int r0 = blockIdx.x * 32;        // 0 or 32
    const int c  = blockIdx.y;
    const int z  = blockIdx.z;
    const int shifts[NK] = {-4, -1, 2, 5, 8};
    const __hip_bfloat16* base = xexp + ((long)z * NEXP + (long)c * NK) * HW;

    for (int idx = t; idx < NK * 34 * 8; idx += 256) {
        int k   = idx / (34 * 8);
        int rem = idx - k * (34 * 8);
        int rr  = rem >> 3, ch = (rem & 7) * 8;
        int grow = (r0 - 1 + rr - shifts[k]) & 63;
        *(bf16x8*)&sd[(k * 34 + rr) * 64 + ch] =
            *(const bf16x8*)(base + (long)k * HW + grow * 64 + ch);
    }
    __syncthreads();

    const int j  = t & 63;
    const int ty = t >> 6;                 // 0..3
    const int pbase = ty * 8;
    const bool topEdge = (r0 == 0)  && (ty == 0);
    const bool botEdge = (r0 == 32) && (ty == 3);

    float2 acc[4];
    #pragma unroll
    for (int i = 0; i < 4; ++i) acc[i] = (float2){0.f, 0.f};

    #pragma unroll
    for (int k = 0; k < NK; ++k) {
        const int s = shifts[k];
        const int cL = (j - 1 - s) & 63;
        const int cC = (j - s) & 63;
        const int cR = (j + 1 - s) & 63;
        const float* wp = &weff[((long)k * C2 + c) * 9];
        float w[9];
        #pragma unroll
        for (int i = 0; i < 9; ++i) w[i] = wp[i];
        if (j == 0)  { w[0] = 0.f; w[3] = 0.f; w[6] = 0.f; }
        if (j == 63) { w[2] = 0.f; w[5] = 0.f; w[8] = 0.f; }
        const __hip_bfloat16* pl = &sd[k * 34 * 64];

        float vL[4], vC[4], vR[4];
        #pragma unroll
        for (int w4 = 0; w4 < 4; ++w4) {
            vL[w4] = __bfloat162float(pl[(pbase + w4) * 64 + cL]);
            vC[w4] = __bfloat162float(pl[(pbase + w4) * 64 + cC]);
            vR[w4] = __bfloat162float(pl[(pbase + w4) * 64 + cR]);
        }
        if (topEdge) { vL[0] = 0.f; vC[0] = 0.f; vR[0] = 0.f; }

        #pragma unroll
        for (int pr = 0; pr < 4; ++pr) {
            #pragma unroll
            for (int u = 0; u < 3; ++u) {
                const int wi  = (2 * pr + u) & 3;
                const int wi2 = (2 * pr + u + 1) & 3;
                acc[pr].x += w[u*3+0] * vL[wi]  + w[u*3+1] * vC[wi]  + w[u*3+2] * vR[wi];
                acc[pr].y += w[u*3+0] * vL[wi2] + w[u*3+1] * vC[wi2] + w[u*3+2] * vR[wi2];
            }
            if (pr < 3) {
                const int na = (2 * pr) & 3, nb = (2 * pr + 1) & 3;
                const int ra = pbase + 2 * pr + 4, rb = pbase + 2 * pr + 5;
                vL[na] = __bfloat162float(pl[ra * 64 + cL]);
                vC[na] = __bfloat162float(pl[ra * 64 + cC]);
                vR[na] = __bfloat162float(pl[ra * 64 + cR]);
                vL[nb] = __bfloat162float(pl[rb * 64 + cL]);
                vC[nb] = __bfloat162float(pl[rb * 64 + cC]);
                vR[nb] = __bfloat162float(pl[rb * 64 + cR]);
                if (botEdge && pr == 2) { vL[nb] = 0.f; vC[nb] = 0.f; vR[nb] = 0.f; }
            }
        }
    }

    long outb = ((long)z * C2 + c) * HW + (long)(r0 + ty * 8) * 64 + j;
    #pragma unroll
    for (int pr = 0; pr < 4; ++pr) {
        merged[outb + (long)(2 * pr) * 64]     = __float2bfloat16(acc[pr].x);
        merged[outb + (long)(2 * pr + 1) * 64] = __float2bfloat16(acc[pr].y);
    }
}

// ---------------------------------------------------------------------------
extern "C" void kernel_launch(void* const* d_in, const int* in_sizes, int n_in,
                              void* d_out, int out_size, void* d_ws, size_t ws_size,
                              hipStream_t stream) {
    const float* x        = (const float*)d_in[0];
    const float* w_expand = (const float*)d_in[1];
    const float* w_path   = (const float*)d_in[2];
    const float* w_mix    = (const float*)d_in[3];
    const float* bn_gamma = (const float*)d_in[4];
    const float* bn_beta  = (const float*)d_in[5];
    const float* bn_mean  = (const float*)d_in[6];
    const float* bn_var   = (const float*)d_in[7];

    char* ws = (char*)d_ws;
    float* weff             = (float*)ws;
    __hip_bfloat16* wexp_bf = (__hip_bfloat16*)(ws + 65536);
    __hip_bfloat16* wmix_bf = (__hip_bfloat16*)(ws + 65536 + 655360);
    const size_t head = 1 << 20;

    const size_t xe_per = (size_t)NEXP * HW * 2;   // 10 MB
    const size_t mg_per = (size_t)C2 * HW * 2;     // 2 MB
    const size_t per_b = xe_per + mg_per;          // 12 MB

    int g = 1;
    if (ws_size > head + per_b) {
        size_t fit = (ws_size - head) / per_b;
        g = (int)(fit < NB ? fit : NB);
        if (g < 1) g = 1;
    }

    char* p = ws + head;
    __hip_bfloat16* xexp   = (__hip_bfloat16*)p; p += (size_t)g * xe_per;
    __hip_bfloat16* merged = (__hip_bfloat16*)p;

    weff_kernel<<<(NK * C2 * 9 + 255) / 256, 256, 0, stream>>>(w_path, weff);
    cvt_bf16_kernel<<<(NEXP * C1 + 255) / 256, 256, 0, stream>>>(w_expand, wexp_bf, NEXP * C1);
    cvt_bf16_kernel<<<(C2 * C2 + 255) / 256, 256, 0, stream>>>(w_mix, wmix_bf, C2 * C2);

    for (int b0 = 0; b0 < NB; b0 += g) {
        int gb = (NB - b0) < g ? (NB - b0) : g;
        // expand: A = wexp_bf [1280x256], B = x [z][256][4096] fp32 -> xexp bf16
        nstream_gemm_kernel<8, true, true><<<dim3(HW / 512, NEXP / 256, gb), 512, 0, stream>>>(
            wexp_bf, x, xexp,
            (long)C1 * HW, (long)NEXP * HW, b0, 0,
            nullptr, nullptr, nullptr, nullptr);
        shift_dw_kernel<<<dim3(2, C2, gb), 256, 0, stream>>>(xexp, weff, merged);
        // mix: A = wmix_bf [256x256], B = merged [z][256][4096] bf16 -> d_out fp32
        nstream_gemm_kernel<2, false, false><<<dim3(HW / 128, 1, gb), 512, 0, stream>>>(
            wmix_bf, merged, d_out,
            (long)C2 * HW, (long)C2 * HW, 0, b0,
            bn_gamma, bn_beta, bn_mean, bn_var);
    }
}